// Round 7
// baseline (103646.423 us; speedup 1.0000x reference)
//
#include <hip/hip_runtime.h>
#include <hip/hip_fp16.h>
#include <math.h>

#define NB 128   // batch
#define NT 256   // time
#define NH 512   // hidden
#define NG 2048  // 4H
#define NV 128   // vocab
#define NLW 32   // decode length
#define AGENT __HIP_MEMORY_SCOPE_AGENT

__device__ __forceinline__ float sigf(float x){ return 1.0f/(1.0f + expf(-x)); }
__device__ __forceinline__ void fma4(float4& a, float s, const float4 w){
  a.x += s*w.x; a.y += s*w.y; a.z += s*w.z; a.w += s*w.w;
}
__device__ __forceinline__ float4 ldh4(const __half* p){
  const __half2* p2 = (const __half2*)p;
  const float2 a = __half22float2(p2[0]);
  const float2 b = __half22float2(p2[1]);
  return make_float4(a.x, a.y, b.x, b.y);
}

// ---------------------------------------------------------------------------
// LDS overlay: phases reuse one shared allocation (barriers separate uses).
// ---------------------------------------------------------------------------
union SmemU {
  struct { float As[64][68]; float Gs[64][33]; } l;                 // LSTM tile
  struct { float As2[64][33]; } g;                                  // small GEMM
  struct { float qs[1024]; float sc[256]; float ps[64];
           float m, lsum, al; } a;                                  // attention
  struct { float cs[512]; float vals[128]; int idxs[128]; } lg;     // logits
};

// ---------------------------------------------------------------------------
// Device-wide barrier: generation counter, agent-scope atomics + fences.
// EVERY resident block must call it the same number of times.
// ---------------------------------------------------------------------------
__device__ __forceinline__ void gridbar(unsigned* cnt, unsigned& gen, unsigned nb) {
  __syncthreads();
  if (threadIdx.x == 0) {
    gen += 1;
    __threadfence();   // release prior global writes (agent scope)
    __hip_atomic_fetch_add(cnt, 1u, __ATOMIC_RELEASE, AGENT);
    const unsigned target = gen * nb;
    int guard = 0;
    while (__hip_atomic_load(cnt, __ATOMIC_ACQUIRE, AGENT) < target) {
      __builtin_amdgcn_s_sleep(2);
      if (++guard > (1 << 18)) break;   // bounded: corrupt>hang if theory wrong
    }
    __threadfence();   // acquire side
  }
  __syncthreads();
}

// ---------------------------------------------------------------------------
// Fused LSTM tile step: 64 b x 32 j (8 n x 4 gates), K staged via LDS in
// 64-chunks. c-state lives in caller registers (2 per thread, pi-mapped).
// Identical accumulation order to round 6 (bit-exact).
// ---------------------------------------------------------------------------
struct SegD {
  const void*  ptr;       // A source [row][K] fp32 or fp16
  const float* W;         // [K][2048]
  const int*   gather;    // optional row gather
  long rowStride;
  int  isHalf;
  int  K;                 // multiple of 64
};

__device__ void lstm_tile(SmemU* U, const SegD* segs, int nseg,
                          const float* x2, const float* Wx, long x2stride,
                          const float* bias, float* creg,
                          float* h_out, __half* y_out, long ystride,
                          int nblk, int bbase) {
  const int tid  = threadIdx.x;
  const int jq   = tid & 7;
  const int gate = jq >> 1;
  const int nq   = jq & 1;
  const int b_l  = (tid >> 3) * 2;
  const int col  = gate*512 + nblk*8 + nq*4;

  float4 acc0 = *(const float4*)(bias + col), acc1 = acc0;

  if (x2) {
    const float4 w0 = *(const float4*)(Wx + col);
    const float4 w1 = *(const float4*)(Wx + NG + col);
    const float* xr0 = x2 + (long)(bbase + b_l    )*x2stride;
    const float* xr1 = x2 + (long)(bbase + b_l + 1)*x2stride;
    fma4(acc0, xr0[0], w0); fma4(acc0, xr0[1], w1);
    fma4(acc1, xr1[0], w0); fma4(acc1, xr1[1], w1);
  }

  const int st_b = tid >> 2;          // 0..63
  const int st_k = (tid & 3) * 16;

  for (int s = 0; s < nseg; ++s) {
    const SegD sg = segs[s];
    const long arow = sg.gather ? sg.gather[bbase + st_b] : (bbase + st_b);
    for (int k0 = 0; k0 < sg.K; k0 += 64) {
      __syncthreads();
      if (sg.isHalf) {
        const __half2* hp = (const __half2*)((const __half*)sg.ptr +
                             arow*sg.rowStride + k0 + st_k);
        #pragma unroll
        for (int i = 0; i < 8; ++i) {
          const float2 f = __half22float2(hp[i]);
          U->l.As[st_k + 2*i    ][st_b] = f.x;
          U->l.As[st_k + 2*i + 1][st_b] = f.y;
        }
      } else {
        const float* ap = (const float*)sg.ptr + arow*sg.rowStride + k0 + st_k;
        #pragma unroll
        for (int i = 0; i < 4; ++i) {
          const float4 f = *(const float4*)(ap + 4*i);
          U->l.As[st_k+4*i  ][st_b] = f.x; U->l.As[st_k+4*i+1][st_b] = f.y;
          U->l.As[st_k+4*i+2][st_b] = f.z; U->l.As[st_k+4*i+3][st_b] = f.w;
        }
      }
      __syncthreads();
      const float* Wrow = sg.W + (long)k0*NG + col;
      #pragma unroll 8
      for (int kk = 0; kk < 64; ++kk) {
        const float4 w = *(const float4*)Wrow;
        const float2 a = *(const float2*)&U->l.As[kk][b_l];
        fma4(acc0, a.x, w);
        fma4(acc1, a.y, w);
        Wrow += NG;
      }
    }
  }

  {
    const int jn = gate*8 + nq*4;
    float* r0 = &U->l.Gs[b_l][jn];
    r0[0]=acc0.x; r0[1]=acc0.y; r0[2]=acc0.z; r0[3]=acc0.w;
    float* r1 = &U->l.Gs[b_l+1][jn];
    r1[0]=acc1.x; r1[1]=acc1.y; r1[2]=acc1.z; r1[3]=acc1.w;
  }
  __syncthreads();
  #pragma unroll
  for (int u = 0; u < 2; ++u) {
    const int pi = tid + u*256;
    const int bl = pi >> 3, nl = pi & 7;
    const float iv = U->l.Gs[bl][nl];
    const float fv = U->l.Gs[bl][8+nl];
    const float gv = U->l.Gs[bl][16+nl];
    const float ov = U->l.Gs[bl][24+nl];
    const float cn = sigf(fv)*creg[u] + sigf(iv)*tanhf(gv);
    const float hn = sigf(ov)*tanhf(cn);
    creg[u] = cn;
    const int b = bbase + bl, n = nblk*8 + nl;
    h_out[(long)b*NH + n] = hn;
    if (y_out) y_out[(long)b*ystride + n] = __float2half_rn(hn);
  }
}

__device__ __forceinline__ void store_c(const float* creg, float* cbuf,
                                        int nblk, int bbase) {
  const int tid = threadIdx.x;
  #pragma unroll
  for (int u = 0; u < 2; ++u) {
    const int pi = tid + u*256;
    const int bl = pi >> 3, nl = pi & 7;
    cbuf[(long)(bbase + bl)*NH + nblk*8 + nl] = creg[u];
  }
}

// ---------------------------------------------------------------------------
// Small dense phase: out[b][j] = sum_s A_s[b]@W + bias, tile 32b x 32j.
// ---------------------------------------------------------------------------
__device__ void gemm_phase(SmemU* U, const float* const* Asrc, const int* Ks,
                           int nseg, const float* W, int N, const float* bias,
                           float* out, int jb, int bq) {
  const int tid = threadIdx.x;
  const int j0 = jb*32;
  const int bbase = bq*32;
  const int b_l = tid >> 3, jq = tid & 7;
  const int st_b = tid >> 3, st_k = (tid & 7)*8;
  float4 acc = {0,0,0,0};
  const float* Wseg = W;
  for (int s = 0; s < nseg; ++s) {
    const float* Amat = Asrc[s];
    const int K = Ks[s];
    for (int k0 = 0; k0 < K; k0 += 64) {
      __syncthreads();
      const float* ap = Amat + (long)(bbase + st_b)*K + k0 + st_k;
      #pragma unroll
      for (int i = 0; i < 8; i += 4) {
        const float4 f = *(const float4*)(ap + i);
        U->g.As2[st_k+i  ][st_b] = f.x; U->g.As2[st_k+i+1][st_b] = f.y;
        U->g.As2[st_k+i+2][st_b] = f.z; U->g.As2[st_k+i+3][st_b] = f.w;
      }
      __syncthreads();
      const float* Wrow = Wseg + (long)k0*N + j0 + jq*4;
      #pragma unroll 8
      for (int kk = 0; kk < 64; ++kk) {
        const float4 w = *(const float4*)Wrow;
        fma4(acc, U->g.As2[kk][b_l], w);
        Wrow += N;
      }
    }
    Wseg += (long)K*N;
  }
  const float4 bv = *(const float4*)(bias + j0 + jq*4);
  acc.x += bv.x; acc.y += bv.y; acc.z += bv.z; acc.w += bv.w;
  *(float4*)(out + (long)(bbase + b_l)*N + j0 + jq*4) = acc;
}

// ---------------------------------------------------------------------------
// Attention phase: one block per batch row; online softmax over T=256.
// ---------------------------------------------------------------------------
__device__ void attn_phase(SmemU* U, const float* query, const __half* enc,
                           float* context, float* attn_out, int step, int b) {
  const int tid = threadIdx.x;
  float* qs = U->a.qs; float* sc = U->a.sc; float* ps = U->a.ps;
  for (int i = tid; i < 1024; i += 256) qs[i] = query[(long)b*1024 + i];
  if (tid == 0) { U->a.m = -1e30f; U->a.lsum = 0.f; U->a.al = 0.f; }
  __syncthreads();
  float4 ctx = {0,0,0,0};
  const __half* encb = enc + (long)b*NT*(2*NH);
  for (int c = 0; c < 4; ++c) {
    const int t0 = c*64;
    {
      const int t_l = tid >> 2, part = tid & 3;
      const __half* er = encb + (long)(t0 + t_l)*1024 + part*256;
      const float* qr = qs + part*256;
      float sv = 0.f;
      for (int k = 0; k < 256; k += 4) {
        const float4 e4 = ldh4(er + k);
        const float4 q4 = *(const float4*)(qr + k);
        sv += e4.x*q4.x + e4.y*q4.y + e4.z*q4.z + e4.w*q4.w;
      }
      sv += __shfl_xor(sv, 1);
      sv += __shfl_xor(sv, 2);
      if (part == 0) sc[t0 + t_l] = sv;
    }
    __syncthreads();
    if (tid < 64) {
      float sv = sc[t0 + tid];
      for (int off = 32; off; off >>= 1) sv = fmaxf(sv, __shfl_xor(sv, off));
      if (tid == 0) {
        const float mn = fmaxf(U->a.m, sv);
        U->a.al = expf(U->a.m - mn);
        U->a.m = mn;
      }
    }
    __syncthreads();
    const float alpha = U->a.al;
    if (tid < 64) {
      float pv = expf(sc[t0 + tid] - U->a.m);
      ps[tid] = pv;
      for (int off = 32; off; off >>= 1) pv += __shfl_xor(pv, off);
      if (tid == 0) U->a.lsum = U->a.lsum*alpha + pv;
    }
    __syncthreads();
    ctx.x *= alpha; ctx.y *= alpha; ctx.z *= alpha; ctx.w *= alpha;
    const __half* ecol = encb + (long)t0*1024 + tid*4;
    for (int t = 0; t < 64; ++t) {
      const float4 e4 = ldh4(ecol + (long)t*1024);
      fma4(ctx, ps[t], e4);
    }
    __syncthreads();
  }
  const float linv = 1.0f / U->a.lsum;
  const long cb = (long)b*1024 + tid*4;
  context[cb+0] = ctx.x*linv; context[cb+1] = ctx.y*linv;
  context[cb+2] = ctx.z*linv; context[cb+3] = ctx.w*linv;
  const float pv = expf(sc[tid] - U->a.m) * linv;
  attn_out[(long)b*(NT*NLW) + (long)tid*NLW + step] = pv;
}

// ---------------------------------------------------------------------------
// Logits + argmax phase (numpy first-index tie-break), 256 threads.
// ---------------------------------------------------------------------------
__device__ void logits_phase(SmemU* U, const float* comb, const float* Wf,
                             const float* bfv, float* out, int sOut,
                             int* tok, int b) {
  const int tid = threadIdx.x;
  for (int i = tid; i < 512; i += 256) U->lg.cs[i] = comb[(long)b*512 + i];
  __syncthreads();
  if (tid < NV) {
    float acc = bfv[tid];
    for (int k = 0; k < 512; k += 4) {
      const float4 c4 = *(const float4*)&U->lg.cs[k];
      acc += c4.x*Wf[(long)(k+0)*NV + tid];
      acc += c4.y*Wf[(long)(k+1)*NV + tid];
      acc += c4.z*Wf[(long)(k+2)*NV + tid];
      acc += c4.w*Wf[(long)(k+3)*NV + tid];
    }
    out[(long)b*sOut + tid] = acc;
    U->lg.vals[tid] = acc; U->lg.idxs[tid] = tid;
  }
  __syncthreads();
  for (int s2 = 64; s2 > 0; s2 >>= 1) {
    if (tid < s2) {
      const float v2 = U->lg.vals[tid+s2]; const int i2 = U->lg.idxs[tid+s2];
      if (v2 > U->lg.vals[tid] ||
          (v2 == U->lg.vals[tid] && i2 < U->lg.idxs[tid])) {
        U->lg.vals[tid] = v2; U->lg.idxs[tid] = i2;
      }
    }
    __syncthreads();
  }
  if (tid == 0) tok[b] = U->lg.idxs[0];
}

// ---------------------------------------------------------------------------
// Persistent encoder: 256 blocks (1/CU). 256 L0 steps then 256 L1 steps,
// one grid barrier per step. c-state in registers; h ping-pong in global.
// ---------------------------------------------------------------------------
struct EncArgs {
  const float *x, *W0ih, *W0hh, *b0, *W1ih, *W1hh, *b1;
  __half *y0h, *ench;
  float *h0[2][2], *h1[2][2], *c0[2], *c1[2];
  unsigned* bar;
};

__global__ __launch_bounds__(256, 2)
void encoder_persistent(EncArgs A) {
  __shared__ SmemU U;
  const int bid   = blockIdx.x;
  const int nblk  = bid & 63;
  const int bhalf = (bid >> 6) & 1;
  const int dir   = bid >> 7;
  const int bbase = bhalf * 64;
  unsigned gen = 0;
  float creg[2] = {0.f, 0.f};

  for (int p = 0; p < NT; ++p) {       // layer 0
    const int t = dir ? (NT-1-p) : p;
    SegD segs[1] = {{ A.h0[dir][p&1], A.W0hh + (long)dir*NH*NG, nullptr, NH, 0, NH }};
    lstm_tile(&U, segs, 1,
              A.x + (long)t*2, A.W0ih + (long)dir*2*NG, (long)NT*2,
              A.b0 + (long)dir*NG, creg,
              A.h0[dir][(p+1)&1],
              A.y0h + (long)t*(2*NH) + (long)dir*NH, (long)NT*2*NH,
              nblk, bbase);
    gridbar(A.bar, gen, 256);
  }
  store_c(creg, A.c0[dir], nblk, bbase);
  creg[0] = 0.f; creg[1] = 0.f;

  for (int p = 0; p < NT; ++p) {       // layer 1 (needs ALL of layer 0: barrier above)
    const int t = dir ? (NT-1-p) : p;
    SegD segs[2] = {
      { A.y0h + (long)t*(2*NH), A.W1ih + (long)dir*(2*NH)*NG, nullptr,
        (long)NT*2*NH, 1, 2*NH },
      { A.h1[dir][p&1], A.W1hh + (long)dir*NH*NG, nullptr, NH, 0, NH } };
    lstm_tile(&U, segs, 2, nullptr, nullptr, 0,
              A.b1 + (long)dir*NG, creg,
              A.h1[dir][(p+1)&1],
              A.ench + (long)t*(2*NH) + (long)dir*NH, (long)NT*2*NH,
              nblk, bbase);
    gridbar(A.bar, gen, 256);
  }
  store_c(creg, A.c1[dir], nblk, bbase);
}

// ---------------------------------------------------------------------------
// Persistent decoder: 128 blocks. 32 steps x 6 phases, barrier after each.
// ---------------------------------------------------------------------------
struct DecArgs {
  const float *dWih, *dWhh, *db, *emb, *Wq, *bq, *Wc, *bc, *Wf, *bf;
  const __half* ench;
  const float *h0f, *h0b, *h1f, *h1b, *c0f, *c0b, *c1f, *c1b;
  float *dh0[2], *dh1[2];
  float *query, *ctx, *comb;
  int* tok;
  float* dout;
  unsigned* bar;
};

__global__ __launch_bounds__(256, 2)
void decoder_persistent(DecArgs A) {
  __shared__ SmemU U;
  const int bid   = blockIdx.x;
  const int tid   = threadIdx.x;
  const int nblk  = bid & 63;
  const int bhalf = bid >> 6;
  const int bbase = bhalf * 64;
  unsigned gen = 0;
  float c0reg[2], c1reg[2];

  // P0: init decoder state
  for (int i = bid*256 + tid; i < NB*NH; i += 128*256) {
    A.dh0[0][i] = A.h0f[i] + A.h0b[i];
    A.dh1[0][i] = A.h1f[i] + A.h1b[i];
  }
  if (bid == 0 && tid < NB) A.tok[tid] = 1;   // SOS
  #pragma unroll
  for (int u = 0; u < 2; ++u) {
    const int pi = tid + u*256;
    const int bl = pi >> 3, nl = pi & 7;
    const long idx = (long)(bbase + bl)*NH + nblk*8 + nl;
    c0reg[u] = A.c0f[idx] + A.c0b[idx];
    c1reg[u] = A.c1f[idx] + A.c1b[idx];
  }
  gridbar(A.bar, gen, 128);

  for (int s = 0; s < NLW; ++s) {
    const int si = s & 1, so = (s+1) & 1;
    {  // P1: LSTM layer 0 (emb[tok] + h)
      SegD segs[2] = {
        { A.emb, A.dWih, A.tok, NH, 0, NH },
        { A.dh0[si], A.dWhh, nullptr, NH, 0, NH } };
      lstm_tile(&U, segs, 2, nullptr, nullptr, 0, A.db, c0reg,
                A.dh0[so], nullptr, 0, nblk, bbase);
    }
    gridbar(A.bar, gen, 128);
    {  // P2: LSTM layer 1
      SegD segs[2] = {
        { A.dh0[so], A.dWih + (long)NH*NG, nullptr, NH, 0, NH },
        { A.dh1[si], A.dWhh + (long)NH*NG, nullptr, NH, 0, NH } };
      lstm_tile(&U, segs, 2, nullptr, nullptr, 0, A.db + NG, c1reg,
                A.dh1[so], nullptr, 0, nblk, bbase);
    }
    gridbar(A.bar, gen, 128);
    {  // P3: query = dec_out @ Wq + bq (N=1024) — 32 jb x 4 bq = 128 blocks
      const float* Asrc[1] = { A.dh1[so] };
      const int Ks[1] = { NH };
      gemm_phase(&U, Asrc, Ks, 1, A.Wq, 2*NH, A.bq, A.query, bid & 31, bid >> 5);
    }
    gridbar(A.bar, gen, 128);
    attn_phase(&U, A.query, A.ench, A.ctx, A.dout + 786432L, s, bid);  // P4
    gridbar(A.bar, gen, 128);
    if (bid < 64) {  // P5: combined = [dec_out, ctx] @ Wc + bc (N=512)
      const float* Asrc[2] = { A.dh1[so], A.ctx };
      const int Ks[2] = { NH, 2*NH };
      gemm_phase(&U, Asrc, Ks, 2, A.Wc, NH, A.bc, A.comb, bid & 15, bid >> 4);
    }
    gridbar(A.bar, gen, 128);
    logits_phase(&U, A.comb, A.Wf, A.bf, A.dout + (long)s*NV, NLW*NV,  // P6
                 A.tok, bid);
    gridbar(A.bar, gen, 128);
  }

  // final: hF from global ping-pong (index 0 after 32 steps), cF from regs
  for (int i = bid*256 + tid; i < NB*NH; i += 128*256) {
    A.dout[524288L + i]         = A.dh0[0][i];
    A.dout[524288L + 65536 + i] = A.dh1[0][i];
  }
  #pragma unroll
  for (int u = 0; u < 2; ++u) {
    const int pi = tid + u*256;
    const int bl = pi >> 3, nl = pi & 7;
    const long idx = (long)(bbase + bl)*NH + nblk*8 + nl;
    A.dout[655360L + idx]         = c0reg[u];
    A.dout[655360L + 65536 + idx] = c1reg[u];
  }
}

// ---------------------------------------------------------------------------
extern "C" void kernel_launch(void* const* d_in, const int* in_sizes, int n_in,
                              void* d_out_v, int out_size, void* d_ws, size_t ws_size,
                              hipStream_t stream) {
  (void)in_sizes; (void)n_in; (void)out_size;
  const float* x    = (const float*)d_in[0];
  const float* W0ih = (const float*)d_in[1];
  const float* W0hh = (const float*)d_in[2];
  const float* b0v  = (const float*)d_in[3];
  const float* W1ih = (const float*)d_in[4];
  const float* W1hh = (const float*)d_in[5];
  const float* b1v  = (const float*)d_in[6];
  const float* dWih = (const float*)d_in[7];
  const float* dWhh = (const float*)d_in[8];
  const float* dbv  = (const float*)d_in[9];
  const float* emb  = (const float*)d_in[10];
  const float* Wq   = (const float*)d_in[11];
  const float* bq   = (const float*)d_in[12];
  const float* Wc   = (const float*)d_in[13];
  const float* bc   = (const float*)d_in[14];
  const float* Wf   = (const float*)d_in[15];
  const float* bfv  = (const float*)d_in[16];

  // ---- workspace layout (float slots) ----
  const long Y0_SLOTS  = 16777216L;   // y0 fp16 [B][T][1024]
  const long ENC_SLOTS = 16777216L;   // enc fp16 [B][T][1024]
  const long ST_SZ     = 1376448L;    // states + scratch + tok + barriers
  const long NEEDED    = Y0_SLOTS + ENC_SLOTS + ST_SZ;   // 34,930,880 fl
  if (ws_size < (size_t)NEEDED*4) return;  // visible fail (zeros)

  float*  ws   = (float*)d_ws;
  __half* y0h  = (__half*)ws;
  __half* ench = (__half*)(ws + Y0_SLOTS);
  float*  st   = ws + Y0_SLOTS + ENC_SLOTS;
  // st layout (floats):
  //   h0[2][2] @0..262144, h1[2][2] @262144, c0[2] @524288, c1[2] @655360,
  //   dh[2][2] @786432, query @1048576, ctx @1179648, comb @1310720,
  //   tok @1376256 (128 ints), barriers @1376384 (2 uints)
  float* dout = (float*)d_out_v;

  hipMemsetAsync(st, 0, ST_SZ*4, stream);

  EncArgs EA;
  EA.x = x; EA.W0ih = W0ih; EA.W0hh = W0hh; EA.b0 = b0v;
  EA.W1ih = W1ih; EA.W1hh = W1hh; EA.b1 = b1v;
  EA.y0h = y0h; EA.ench = ench;
  EA.h0[0][0] = st+0;      EA.h0[0][1] = st+65536;
  EA.h0[1][0] = st+131072; EA.h0[1][1] = st+196608;
  EA.h1[0][0] = st+262144; EA.h1[0][1] = st+327680;
  EA.h1[1][0] = st+393216; EA.h1[1][1] = st+458752;
  EA.c0[0] = st+524288; EA.c0[1] = st+589824;
  EA.c1[0] = st+655360; EA.c1[1] = st+720896;
  EA.bar = (unsigned*)(st + 1376384);
  encoder_persistent<<<256, 256, 0, stream>>>(EA);

  DecArgs DA;
  DA.dWih = dWih; DA.dWhh = dWhh; DA.db = dbv; DA.emb = emb;
  DA.Wq = Wq; DA.bq = bq; DA.Wc = Wc; DA.bc = bc; DA.Wf = Wf; DA.bf = bfv;
  DA.ench = ench;
  DA.h0f = EA.h0[0][0]; DA.h0b = EA.h0[1][0];   // ping-pong idx 0 after 256 steps
  DA.h1f = EA.h1[0][0]; DA.h1b = EA.h1[1][0];
  DA.c0f = EA.c0[0]; DA.c0b = EA.c0[1];
  DA.c1f = EA.c1[0]; DA.c1b = EA.c1[1];
  DA.dh0[0] = st+786432; DA.dh0[1] = st+851968;
  DA.dh1[0] = st+917504; DA.dh1[1] = st+983040;
  DA.query = st+1048576; DA.ctx = st+1179648; DA.comb = st+1310720;
  DA.tok = (int*)(st + 1376256);
  DA.dout = dout;
  DA.bar = (unsigned*)(st + 1376384) + 1;
  decoder_persistent<<<128, 256, 0, stream>>>(DA);
}

// Round 9
// 87183.698 us; speedup vs baseline: 1.1888x; 1.1888x over previous
//
#include <hip/hip_runtime.h>
#include <hip/hip_fp16.h>
#include <math.h>

#define AGENT __HIP_MEMORY_SCOPE_AGENT

__device__ __forceinline__ float sigf(float x){ return 1.0f/(1.0f+expf(-x)); }
__device__ __forceinline__ float4 ldh4(const __half* p){
  const __half2* p2=(const __half2*)p;
  const float2 a=__half22float2(p2[0]), b=__half22float2(p2[1]);
  return make_float4(a.x,a.y,b.x,b.y);
}

// device-wide barrier (generation counter; agent scope). Every block in the
// group calls it the same number of times.
__device__ __forceinline__ void gridbar(unsigned* cnt, unsigned& gen, unsigned nb){
  __syncthreads();
  if(threadIdx.x==0){
    gen++;
    __threadfence();
    __hip_atomic_fetch_add(cnt,1u,__ATOMIC_RELEASE,AGENT);
    const unsigned tgt=gen*nb; int guard=0;
    while(__hip_atomic_load(cnt,__ATOMIC_ACQUIRE,AGENT)<tgt){
      __builtin_amdgcn_s_sleep(2);
      if(++guard>(1<<18)) break;
    }
    __threadfence();
  }
  __syncthreads();
}

struct ASeg { const void* ptr; long rowStride; int isHalf; const int* gather; int K; };

// stage rows [kl,kl+32) of one A segment into As[32][128]
__device__ __forceinline__ void stageA(float* As, const ASeg sg, int kl){
  const int st_b = threadIdx.x & 127;
  const int kh = (threadIdx.x >> 7) * 16;
  const long row = sg.gather ? (long)sg.gather[st_b] : (long)st_b;
  if(sg.isHalf){
    const __half* p=(const __half*)sg.ptr + row*sg.rowStride + kl + kh;
    #pragma unroll
    for(int i=0;i<16;i+=4){
      const float4 f=ldh4(p+i);
      As[(kh+i)*128+st_b]=f.x; As[(kh+i+1)*128+st_b]=f.y;
      As[(kh+i+2)*128+st_b]=f.z; As[(kh+i+3)*128+st_b]=f.w;
    }
  } else {
    const float* p=(const float*)sg.ptr + row*sg.rowStride + kl + kh;
    #pragma unroll
    for(int i=0;i<16;i+=4){
      const float4 f=*(const float4*)(p+i);
      As[(kh+i)*128+st_b]=f.x; As[(kh+i+1)*128+st_b]=f.y;
      As[(kh+i+2)*128+st_b]=f.z; As[(kh+i+3)*128+st_b]=f.w;
    }
  }
}

// 128b x C cols GEMM, K split across 4 waves by k%4 interleave; partials to Gs.
// NOTE: the epilogue SUMS the 4 per-wave partials, so per-thread accumulators
// must NOT be pre-seeded with terms that all waves would duplicate.
template<int C>
__device__ void gemmK(float* As, float* Ws, float* Gs,
                      const ASeg* segs, int nseg, const float* Wre, float* acc){
  constexpr int CJ = C/4;
  const int tid=threadIdx.x, w=tid>>6, lane=tid&63;
  const int bg=lane&15, cg=lane>>4;
  int kg=0;
  for(int s=0;s<nseg;++s){
    for(int kl=0;kl<segs[s].K;kl+=32,kg+=32){
      __syncthreads();
      stageA(As,segs[s],kl);
      if(tid<32*C/4) *(float4*)(Ws+tid*4)=*(const float4*)(Wre+(long)kg*C+tid*4);
      __syncthreads();
      #pragma unroll
      for(int i=0;i<8;++i){
        const int k=w+i*4;
        const float4 a0=*(const float4*)(As+k*128+bg*8);
        const float4 a1=*(const float4*)(As+k*128+bg*8+4);
        const float* wp=Ws+k*C+cg*CJ;
        #pragma unroll
        for(int j=0;j<CJ;++j){
          const float wv=wp[j];
          acc[0*CJ+j]+=a0.x*wv; acc[1*CJ+j]+=a0.y*wv;
          acc[2*CJ+j]+=a0.z*wv; acc[3*CJ+j]+=a0.w*wv;
          acc[4*CJ+j]+=a1.x*wv; acc[5*CJ+j]+=a1.y*wv;
          acc[6*CJ+j]+=a1.z*wv; acc[7*CJ+j]+=a1.w*wv;
        }
      }
    }
  }
  __syncthreads();
  #pragma unroll
  for(int bi=0;bi<8;++bi){
    float* gp=Gs+((long)w*128+bg*8+bi)*C+cg*CJ;
    #pragma unroll
    for(int j=0;j<CJ;++j) gp[j]=acc[bi*CJ+j];
  }
  __syncthreads();
}

// ---------------------------------------------------------------------------
// Encoder: 512 blocks (dir = bid>>8, np = bid&255 -> 2 n's = 8 gate-cols).
// Weight slices pre-relaid once; per step staged via LDS (flush-immune).
// ---------------------------------------------------------------------------
struct EncA {
  const float *x,*W0ih,*W0hh,*b0,*W1ih,*W1hh,*b1;
  float *WreL0,*BreL0,*WxRe,*WreL1,*BreL1;
  __half *y0h,*ench;
  float *h0[2][2],*h1[2][2],*c0[2],*c1[2];
  unsigned* cnt;  // [0],[1]=per-dir, [2]=full
};

__global__ __launch_bounds__(256,2) void enc_kernel(EncA A){
  extern __shared__ float sm[];
  float* As=sm;            // 4096
  float* Ws=sm+4096;       // 256
  float* Gs=sm+4352;       // 4096
  float* xs=sm+8448;       // 256
  const int tid=threadIdx.x, bid=blockIdx.x;
  const int dir=bid>>8, np=bid&255;
  unsigned genD=0, genF=0;

  // ---- one-time re-layout of this block's weight slices ----
  float* wl0=A.WreL0+(long)bid*512*8;
  for(int i=tid;i<512*8;i+=256){
    const int k=i>>3,c=i&7,g=c>>1,u=c&1;
    wl0[i]=A.W0hh[(long)dir*512*2048+(long)k*2048+g*512+np*2+u];
  }
  float* wl1=A.WreL1+(long)bid*1536*8;
  for(int i=tid;i<1536*8;i+=256){
    const int k=i>>3,c=i&7,g=c>>1,u=c&1,col=g*512+np*2+u;
    wl1[i]=(k<1024)? A.W1ih[(long)dir*1024*2048+(long)k*2048+col]
                   : A.W1hh[(long)dir*512*2048+(long)(k-1024)*2048+col];
  }
  if(tid<8){const int g=tid>>1,u=tid&1;
    A.BreL0[bid*8+tid]=A.b0[dir*2048+g*512+np*2+u];
    A.BreL1[bid*8+tid]=A.b1[dir*2048+g*512+np*2+u];}
  if(tid<16){const int u2=tid>>3,c=tid&7,g=c>>1,u=c&1;
    A.WxRe[bid*16+tid]=A.W0ih[(long)dir*2*2048+(long)u2*2048+g*512+np*2+u];}
  __syncthreads();

  float creg=0.f;
  // ---- layer 0 ----
  for(int p=0;p<256;++p){
    const int t=dir?(255-p):p;
    if(tid<128){ xs[tid*2]=A.x[(long)tid*512+t*2]; xs[tid*2+1]=A.x[(long)tid*512+t*2+1]; }
    float acc[16];
    #pragma unroll
    for(int i=0;i<16;++i) acc[i]=0.f;
    __syncthreads();
    ASeg sg{A.h0[dir][p&1],512,0,nullptr,512};
    gemmK<8>(As,Ws,Gs,&sg,1,wl0,acc);
    {
      const int b=tid>>1,nl=tid&1;
      const float x0=xs[b*2], x1=xs[b*2+1];
      float g4[4];
      #pragma unroll
      for(int g=0;g<4;++g){const int c=g*2+nl;
        g4[g]=Gs[0*1024+b*8+c]+Gs[1*1024+b*8+c]+Gs[2*1024+b*8+c]+Gs[3*1024+b*8+c]
             +A.BreL0[bid*8+c]
             +x0*A.WxRe[bid*16+c]+x1*A.WxRe[bid*16+8+c];}   // x-term added ONCE
      const float cn=sigf(g4[1])*creg+sigf(g4[0])*tanhf(g4[2]);
      const float hn=sigf(g4[3])*tanhf(cn);
      creg=cn;
      const int n=np*2+nl;
      A.h0[dir][(p+1)&1][(long)b*512+n]=hn;
      A.y0h[(long)b*262144+(long)t*1024+dir*512+n]=__float2half_rn(hn);
    }
    gridbar(&A.cnt[dir],genD,256);
  }
  {const int b=tid>>1,nl=tid&1; A.c0[dir][(long)b*512+np*2+nl]=creg;}
  creg=0.f;
  gridbar(&A.cnt[2],genF,512);   // all of layer 0 (both dirs) complete

  // ---- layer 1 ----
  for(int p=0;p<256;++p){
    const int t=dir?(255-p):p;
    float acc[16];
    #pragma unroll
    for(int i=0;i<16;++i) acc[i]=0.f;
    ASeg sg[2]={{A.y0h+(long)t*1024,262144,1,nullptr,1024},
                {A.h1[dir][p&1],512,0,nullptr,512}};
    gemmK<8>(As,Ws,Gs,sg,2,wl1,acc);
    {
      const int b=tid>>1,nl=tid&1;
      float g4[4];
      #pragma unroll
      for(int g=0;g<4;++g){const int c=g*2+nl;
        g4[g]=Gs[0*1024+b*8+c]+Gs[1*1024+b*8+c]+Gs[2*1024+b*8+c]+Gs[3*1024+b*8+c]
             +A.BreL1[bid*8+c];}
      const float cn=sigf(g4[1])*creg+sigf(g4[0])*tanhf(g4[2]);
      const float hn=sigf(g4[3])*tanhf(cn);
      creg=cn;
      const int n=np*2+nl;
      A.h1[dir][(p+1)&1][(long)b*512+n]=hn;
      A.ench[(long)b*262144+(long)t*1024+dir*512+n]=__float2half_rn(hn);
    }
    gridbar(&A.cnt[dir],genD,256);
  }
  {const int b=tid>>1,nl=tid&1; A.c1[dir][(long)b*512+np*2+nl]=creg;}
}

// ---------------------------------------------------------------------------
// Decoder: 256 blocks, 8 barrier-phases per step.
// ---------------------------------------------------------------------------
struct DecA {
  const float *dWih,*dWhh,*db,*emb,*Wq,*bq,*Wc,*bc,*Wf,*bf;
  const __half* ench;
  float *WreD0,*BreD0,*WreD1,*BreD1,*WreQ,*BreQ,*WreC,*BreC,*WreF,*BreF;
  const float *h0[2],*h1[2],*c0[2],*c1[2];
  float *dh0[2],*dh1[2],*query,*ctx,*comb,*pctx,*pm,*pl,*psc,*lgscr;
  int* tok;
  float* dout;
  unsigned* cnt;
};

__global__ __launch_bounds__(256,2) void dec_kernel(DecA A){
  extern __shared__ float sm[];
  float* As=sm;          // 4096
  float* Ws=sm+4096;     // 512
  float* Gs=sm+4608;     // 8192
  float* attnS=Gs;       // overlay: qs[1024], scl[128], psl[128], red[...]
  const int tid=threadIdx.x, bid=blockIdx.x;
  unsigned gen=0;

  // ---- one-time re-layout ----
  if(bid<128){
    float* w0=A.WreD0+(long)bid*1024*16;
    for(int i=tid;i<1024*16;i+=256){
      const int k=i>>4,c=i&15,g=c>>2,u=c&3,col=g*512+bid*4+u;
      w0[i]=(k<512)?A.dWih[(long)k*2048+col]:A.dWhh[(long)(k-512)*2048+col];
    }
    if(tid<16){const int g=tid>>2,u=tid&3;A.BreD0[bid*16+tid]=A.db[g*512+bid*4+u];}
    float* wc=A.WreC+(long)bid*1536*4;
    for(int i=tid;i<1536*4;i+=256){const int k=i>>2,c=i&3;
      wc[i]=A.Wc[(long)k*512+bid*4+c];}
    if(tid<4)A.BreC[bid*4+tid]=A.bc[bid*4+tid];
  } else {
    const int b2=bid-128;
    float* w1=A.WreD1+(long)b2*1024*16;
    for(int i=tid;i<1024*16;i+=256){
      const int k=i>>4,c=i&15,g=c>>2,u=c&3,col=g*512+b2*4+u;
      w1[i]=(k<512)?A.dWih[512L*2048+(long)k*2048+col]
                   :A.dWhh[512L*2048+(long)(k-512)*2048+col];
    }
    if(tid<16){const int g=tid>>2,u=tid&3;A.BreD1[b2*16+tid]=A.db[2048+g*512+b2*4+u];}
  }
  {
    float* wq=A.WreQ+(long)bid*512*4;
    for(int i=tid;i<512*4;i+=256){const int k=i>>2,c=i&3;
      wq[i]=A.Wq[(long)k*1024+bid*4+c];}
    if(tid<4)A.BreQ[bid*4+tid]=A.bq[bid*4+tid];
  }
  if(bid<32){
    float* wf=A.WreF+(long)bid*512*4;
    for(int i=tid;i<512*4;i+=256){const int k=i>>2,c=i&3;
      wf[i]=A.Wf[(long)k*128+bid*4+c];}
    if(tid<4)A.BreF[bid*4+tid]=A.bf[bid*4+tid];
  }
  // ---- init decoder state ----
  for(int i=bid*256+tid;i<65536;i+=256*256){
    A.dh0[0][i]=A.h0[0][i]+A.h0[1][i];
    A.dh1[0][i]=A.h1[0][i]+A.h1[1][i];
  }
  if(bid==0&&tid<128)A.tok[tid]=1;   // SOS
  float creg[2];
  if(bid<128){
    #pragma unroll
    for(int u=0;u<2;++u){const int cl=tid*2+u,b=cl>>2,nl=cl&3;
      const long idx=(long)b*512+bid*4+nl;
      creg[u]=A.c0[0][idx]+A.c0[1][idx];}
  } else {
    #pragma unroll
    for(int u=0;u<2;++u){const int cl=tid*2+u,b=cl>>2,nl=cl&3;
      const long idx=(long)b*512+(bid-128)*4+nl;
      creg[u]=A.c1[0][idx]+A.c1[1][idx];}
  }
  gridbar(A.cnt,gen,256);

  for(int s=0;s<32;++s){
    const int si=s&1,so=(s+1)&1;
    // P1: LSTM layer 0 (blocks 0-127)
    if(bid<128){
      float acc16[32];
      #pragma unroll
      for(int i=0;i<32;++i)acc16[i]=0.f;
      ASeg sg[2]={{A.emb,512,0,A.tok,512},{A.dh0[si],512,0,nullptr,512}};
      gemmK<16>(As,Ws,Gs,sg,2,A.WreD0+(long)bid*1024*16,acc16);
      #pragma unroll
      for(int u=0;u<2;++u){
        const int cl=tid*2+u,b=cl>>2,nl=cl&3;
        float g4[4];
        #pragma unroll
        for(int g=0;g<4;++g){const int c=g*4+nl;
          g4[g]=Gs[0*2048+b*16+c]+Gs[1*2048+b*16+c]+Gs[2*2048+b*16+c]+Gs[3*2048+b*16+c]
               +A.BreD0[bid*16+c];}
        const float cn=sigf(g4[1])*creg[u]+sigf(g4[0])*tanhf(g4[2]);
        const float hn=sigf(g4[3])*tanhf(cn);
        creg[u]=cn;
        A.dh0[so][(long)b*512+bid*4+nl]=hn;
      }
    }
    gridbar(A.cnt,gen,256);
    // P2: LSTM layer 1 (blocks 128-255)
    if(bid>=128){
      const int b2=bid-128;
      float acc16[32];
      #pragma unroll
      for(int i=0;i<32;++i)acc16[i]=0.f;
      ASeg sg[2]={{A.dh0[so],512,0,nullptr,512},{A.dh1[si],512,0,nullptr,512}};
      gemmK<16>(As,Ws,Gs,sg,2,A.WreD1+(long)b2*1024*16,acc16);
      #pragma unroll
      for(int u=0;u<2;++u){
        const int cl=tid*2+u,b=cl>>2,nl=cl&3;
        float g4[4];
        #pragma unroll
        for(int g=0;g<4;++g){const int c=g*4+nl;
          g4[g]=Gs[0*2048+b*16+c]+Gs[1*2048+b*16+c]+Gs[2*2048+b*16+c]+Gs[3*2048+b*16+c]
               +A.BreD1[b2*16+c];}
        const float cn=sigf(g4[1])*creg[u]+sigf(g4[0])*tanhf(g4[2]);
        const float hn=sigf(g4[3])*tanhf(cn);
        creg[u]=cn;
        A.dh1[so][(long)b*512+b2*4+nl]=hn;
      }
    }
    gridbar(A.cnt,gen,256);
    // P3: query (all blocks, 4 cols each)
    {
      float acc[8];
      #pragma unroll
      for(int i=0;i<8;++i)acc[i]=0.f;
      ASeg sg{A.dh1[so],512,0,nullptr,512};
      gemmK<4>(As,Ws,Gs,&sg,1,A.WreQ+(long)bid*512*4,acc);
      #pragma unroll
      for(int u=0;u<2;++u){const int oi=tid*2+u,b=oi>>2,c=oi&3;
        const float v=Gs[0*512+b*4+c]+Gs[1*512+b*4+c]+Gs[2*512+b*4+c]+Gs[3*512+b*4+c]
                     +A.BreQ[bid*4+c];
        A.query[(long)b*1024+bid*4+c]=v;}
    }
    gridbar(A.cnt,gen,256);
    // P4a: attention partial (b=bid&127, t-half=bid>>7)
    {
      const int b=bid&127, th=bid>>7;
      float* qs=attnS; float* scl=attnS+1024; float* psl=attnS+1152; float* red=attnS+1280;
      for(int i=tid;i<1024;i+=256) qs[i]=A.query[(long)b*1024+i];
      __syncthreads();
      {
        const int tl=tid>>1, part=tid&1;
        const __half* er=A.ench+((long)b*256+th*128+tl)*1024+part*512;
        const float* qr=qs+part*512;
        float sv=0.f;
        for(int k=0;k<512;k+=8){
          const float4 e0=ldh4(er+k),e1=ldh4(er+k+4);
          const float4 q0=*(const float4*)(qr+k),q1=*(const float4*)(qr+k+4);
          sv+=e0.x*q0.x+e0.y*q0.y+e0.z*q0.z+e0.w*q0.w;
          sv+=e1.x*q1.x+e1.y*q1.y+e1.z*q1.z+e1.w*q1.w;
        }
        sv+=__shfl_xor(sv,1);
        if(part==0)scl[tl]=sv;
      }
      __syncthreads();
      if(tid<64){float m=fmaxf(scl[tid],scl[tid+64]);
        for(int o=32;o;o>>=1)m=fmaxf(m,__shfl_xor(m,o));
        if(tid==0)red[0]=m;}
      __syncthreads();
      const float m=red[0];
      if(tid<128)psl[tid]=expf(scl[tid]-m);
      __syncthreads();
      if(tid<64){float l=psl[tid]+psl[tid+64];
        for(int o=32;o;o>>=1)l+=__shfl_xor(l,o);
        if(tid==0)red[1]=l;}
      float4 cx={0,0,0,0};
      const __half* eb=A.ench+((long)b*256+th*128)*1024+tid*4;
      #pragma unroll 4
      for(int t2=0;t2<128;++t2){
        const float4 e=ldh4(eb+(long)t2*1024);
        const float pv=psl[t2];
        cx.x+=pv*e.x; cx.y+=pv*e.y; cx.z+=pv*e.z; cx.w+=pv*e.w;
      }
      __syncthreads();
      float* pc=A.pctx+((long)b*2+th)*1024+tid*4;
      pc[0]=cx.x;pc[1]=cx.y;pc[2]=cx.z;pc[3]=cx.w;
      if(tid==0){A.pm[b*2+th]=red[0];A.pl[b*2+th]=red[1];}
      if(tid<128)A.psc[(long)b*256+th*128+tid]=scl[tid];
    }
    gridbar(A.cnt,gen,256);
    // P4b: merge (blocks 0-127)
    if(bid<128){
      const int b=bid;
      const float m0=A.pm[b*2],m1=A.pm[b*2+1];
      const float l0=A.pl[b*2],l1=A.pl[b*2+1];
      const float m=fmaxf(m0,m1);
      const float e0=expf(m0-m),e1=expf(m1-m);
      const float linv=1.f/(l0*e0+l1*e1);
      const float4 p0=*(const float4*)(A.pctx+((long)b*2)*1024+tid*4);
      const float4 p1=*(const float4*)(A.pctx+((long)b*2+1)*1024+tid*4);
      float* cp=A.ctx+(long)b*1024+tid*4;
      cp[0]=(p0.x*e0+p1.x*e1)*linv; cp[1]=(p0.y*e0+p1.y*e1)*linv;
      cp[2]=(p0.z*e0+p1.z*e1)*linv; cp[3]=(p0.w*e0+p1.w*e1)*linv;
      const float pr=expf(A.psc[(long)b*256+tid]-m)*linv;
      A.dout[786432+(long)b*8192+tid*32+s]=pr;
    }
    gridbar(A.cnt,gen,256);
    // P5: combined (blocks 0-127, 4 cols each)
    if(bid<128){
      float acc[8];
      #pragma unroll
      for(int i=0;i<8;++i)acc[i]=0.f;
      ASeg sg[2]={{A.dh1[so],512,0,nullptr,512},{A.ctx,1024,0,nullptr,1024}};
      gemmK<4>(As,Ws,Gs,sg,2,A.WreC+(long)bid*1536*4,acc);
      #pragma unroll
      for(int u=0;u<2;++u){const int oi=tid*2+u,b=oi>>2,c=oi&3;
        const float v=Gs[0*512+b*4+c]+Gs[1*512+b*4+c]+Gs[2*512+b*4+c]+Gs[3*512+b*4+c]
                     +A.BreC[bid*4+c];
        A.comb[(long)b*512+bid*4+c]=v;}
    }
    gridbar(A.cnt,gen,256);
    // P6a: logits (blocks 0-31, 4 cols each)
    if(bid<32){
      float acc[8];
      #pragma unroll
      for(int i=0;i<8;++i)acc[i]=0.f;
      ASeg sg{A.comb,512,0,nullptr,512};
      gemmK<4>(As,Ws,Gs,&sg,1,A.WreF+(long)bid*512*4,acc);
      #pragma unroll
      for(int u=0;u<2;++u){const int oi=tid*2+u,b=oi>>2,c=oi&3;
        const float v=Gs[0*512+b*4+c]+Gs[1*512+b*4+c]+Gs[2*512+b*4+c]+Gs[3*512+b*4+c]
                     +A.BreF[bid*4+c];
        A.lgscr[(long)b*128+bid*4+c]=v;}
    }
    gridbar(A.cnt,gen,256);
    // P6b: argmax + logits out (blocks 0-127)
    if(bid<128){
      const int b=bid;
      float* vals=attnS; int* idxs=(int*)(attnS+256);
      if(tid<128){const float v=A.lgscr[(long)b*128+tid];
        vals[tid]=v; idxs[tid]=tid;
        A.dout[(long)b*4096+s*128+tid]=v;}
      __syncthreads();
      for(int s2=64;s2;s2>>=1){
        if(tid<s2){const float v2=vals[tid+s2];const int i2=idxs[tid+s2];
          if(v2>vals[tid]||(v2==vals[tid]&&i2<idxs[tid])){vals[tid]=v2;idxs[tid]=i2;}}
        __syncthreads();
      }
      if(tid==0)A.tok[b]=idxs[0];
    }
    gridbar(A.cnt,gen,256);
  }
  // final state outputs
  {
    const int i=bid*256+tid;   // exactly 65536
    A.dout[524288+i]=A.dh0[0][i];
    A.dout[524288+65536+i]=A.dh1[0][i];
  }
  if(bid<128){
    #pragma unroll
    for(int u=0;u<2;++u){const int cl=tid*2+u,b=cl>>2,nl=cl&3;
      A.dout[655360+(long)b*512+bid*4+nl]=creg[u];}
  } else {
    #pragma unroll
    for(int u=0;u<2;++u){const int cl=tid*2+u,b=cl>>2,nl=cl&3;
      A.dout[655360+65536+(long)b*512+(bid-128)*4+nl]=creg[u];}
  }
}

// ---------------------------------------------------------------------------
extern "C" void kernel_launch(void* const* d_in, const int* in_sizes, int n_in,
                              void* d_out_v, int out_size, void* d_ws, size_t ws_size,
                              hipStream_t stream) {
  (void)in_sizes;(void)n_in;(void)out_size;
  const float* x    =(const float*)d_in[0];
  const float* W0ih =(const float*)d_in[1];
  const float* W0hh =(const float*)d_in[2];
  const float* b0v  =(const float*)d_in[3];
  const float* W1ih =(const float*)d_in[4];
  const float* W1hh =(const float*)d_in[5];
  const float* b1v  =(const float*)d_in[6];
  const float* dWih =(const float*)d_in[7];
  const float* dWhh =(const float*)d_in[8];
  const float* dbv  =(const float*)d_in[9];
  const float* emb  =(const float*)d_in[10];
  const float* Wq   =(const float*)d_in[11];
  const float* bq   =(const float*)d_in[12];
  const float* Wc   =(const float*)d_in[13];
  const float* bc   =(const float*)d_in[14];
  const float* Wf   =(const float*)d_in[15];
  const float* bfv  =(const float*)d_in[16];

  const long Y0=16777216L, ENC=16777216L, STSZ=1688576L, WRE=13981312L;
  const long NEEDED=Y0+ENC+STSZ+WRE;   // 49,224,320 floats ≈ 197 MB
  if(ws_size<(size_t)NEEDED*4) return;

  float*  ws  =(float*)d_ws;
  __half* y0h =(__half*)ws;
  __half* ench=(__half*)(ws+Y0);
  float*  st  =ws+Y0+ENC;
  float*  wb  =st+STSZ;

  hipMemsetAsync(st,0,STSZ*4,stream);

  EncA EA;
  EA.x=x; EA.W0ih=W0ih; EA.W0hh=W0hh; EA.b0=b0v;
  EA.W1ih=W1ih; EA.W1hh=W1hh; EA.b1=b1v;
  EA.WreL0=wb; EA.BreL0=wb+2097152; EA.WxRe=wb+2101248;
  EA.WreL1=wb+2109440; EA.BreL1=wb+8400896;
  EA.y0h=y0h; EA.ench=ench;
  EA.h0[0][0]=st+0;      EA.h0[0][1]=st+65536;
  EA.h0[1][0]=st+131072; EA.h0[1][1]=st+196608;
  EA.h1[0][0]=st+262144; EA.h1[0][1]=st+327680;
  EA.h1[1][0]=st+393216; EA.h1[1][1]=st+458752;
  EA.c0[0]=st+524288; EA.c0[1]=st+589824;
  EA.c1[0]=st+655360; EA.c1[1]=st+720896;
  EA.cnt=(unsigned*)(st+1688192);
  enc_kernel<<<512,256,34816,stream>>>(EA);

  DecA DA;
  DA.dWih=dWih; DA.dWhh=dWhh; DA.db=dbv; DA.emb=emb;
  DA.Wq=Wq; DA.bq=bq; DA.Wc=Wc; DA.bc=bc; DA.Wf=Wf; DA.bf=bfv;
  DA.ench=ench;
  DA.WreD0=wb+8404992;  DA.BreD0=wb+10502144;
  DA.WreD1=wb+10504192; DA.BreD1=wb+12601344;
  DA.WreQ=wb+12603392;  DA.BreQ=wb+13127680;
  DA.WreC=wb+13128704;  DA.BreC=wb+13915136;
  DA.WreF=wb+13915648;  DA.BreF=wb+13981184;
  DA.h0[0]=st+0; DA.h0[1]=st+131072;           // h0[dir][0] after 256 steps
  DA.h1[0]=st+262144; DA.h1[1]=st+393216;
  DA.c0[0]=st+524288; DA.c0[1]=st+589824;
  DA.c1[0]=st+655360; DA.c1[1]=st+720896;
  DA.dh0[0]=st+786432; DA.dh0[1]=st+851968;
  DA.dh1[0]=st+917504; DA.dh1[1]=st+983040;
  DA.query=st+1048576; DA.ctx=st+1179648; DA.comb=st+1310720;
  DA.pctx=st+1376256; DA.pm=st+1638400; DA.pl=st+1638656;
  DA.psc=st+1638912; DA.lgscr=st+1671680;
  DA.tok=(int*)(st+1688064);
  DA.dout=(float*)d_out_v;
  DA.cnt=(unsigned*)(st+1688192)+3;
  dec_kernel<<<256,256,51200,stream>>>(DA);
}